// Round 7
// baseline (199.569 us; speedup 1.0000x reference)
//
#include <hip/hip_runtime.h>
#include <stdint.h>

#define S_LEN 4096
#define EMB   1024
#define HEAD  64

typedef short bf16x8 __attribute__((ext_vector_type(8)));
typedef float f32x4  __attribute__((ext_vector_type(4)));

// scale = 1/sqrt(64) = 0.125, folded with log2(e) so softmax uses exp2
#define QSCALE 0.18033688011112042f

__device__ __forceinline__ unsigned short f2bf(float f) {
    union { float f; uint32_t u; } v; v.f = f;
    uint32_t r = v.u + 0x7fffu + ((v.u >> 16) & 1u);
    return (unsigned short)(r >> 16);
}

// ---------------------------------------------------------------------------
// Kernel 0: W prep.  wt[m][n][k] = bf16(W_m[k][n]).  Coalesced via LDS
// transpose: 48 blocks = 3 mats x 16 k-chunks of 64.
// ---------------------------------------------------------------------------
__global__ void wprep_kernel(const float* __restrict__ Wq,
                             const float* __restrict__ Wk,
                             const float* __restrict__ Wv,
                             unsigned short* __restrict__ wt) {
    __shared__ float t[64][65];
    const int tid = threadIdx.x;
    const int m   = blockIdx.x >> 4;
    const int k0  = (blockIdx.x & 15) << 6;
    const float* W = (m == 0) ? Wq : (m == 1) ? Wk : Wv;
    for (int i = 0; i < 4; ++i) {
        const int k  = (tid >> 4) + i * 16;
        const int n4 = (tid & 15) << 2;
        float4 v = *(const float4*)&W[(k0 + k) * 64 + n4];
        t[k][n4 + 0] = v.x; t[k][n4 + 1] = v.y;
        t[k][n4 + 2] = v.z; t[k][n4 + 3] = v.w;
    }
    __syncthreads();
    const int n = tid >> 2, kq = (tid & 3) << 4;
    __align__(16) unsigned short u[16];
    for (int i = 0; i < 16; ++i) u[i] = f2bf(t[kq + i][n]);
    *(int4*)&wt[(m * 64 + n) * 1024 + k0 + kq]     = *(int4*)&u[0];
    *(int4*)&wt[(m * 64 + n) * 1024 + k0 + kq + 8] = *(int4*)&u[8];
}

// ---------------------------------------------------------------------------
// Kernel 1: fused QKV projection, bf16 MFMA GEMM, double-buffered LDS.
//   (unchanged from R6 — its true duration becomes visible this round)
// ---------------------------------------------------------------------------
__global__ __launch_bounds__(512, 4) void qkv_kernel(
    const float* __restrict__ x, const unsigned short* __restrict__ wt,
    const float* __restrict__ bq, const float* __restrict__ bk,
    const float* __restrict__ bv,
    unsigned short* __restrict__ Qp, unsigned short* __restrict__ Kp,
    unsigned short* __restrict__ Vt) {

    __shared__ __align__(16) unsigned short xs[2][32 * 72];   // 9.2 KB
    __shared__ __align__(16) unsigned short ws[2][192 * 72];  // 55.3 KB

    const int tid  = threadIdx.x;
    const int lane = tid & 63;
    const int w    = tid >> 6;        // 0..7
    const int wm   = w & 1;           // 0..1  (16-row half)
    const int wn   = w >> 1;          // 0..3  (48-col strip)
    const int quad = lane >> 4;
    const int lid  = lane & 15;
    const int row0 = blockIdx.x * 32;

    f32x4 acc[3];
    for (int j = 0; j < 3; ++j) acc[j] = (f32x4){0.f, 0.f, 0.f, 0.f};

#define STAGE(BUF, K0)                                                         \
    do {                                                                       \
        {   /* x: 32 rows x 64 k fp32 -> bf16, one float4 per thread */        \
            int r = tid >> 4, c4 = (tid & 15) << 2;                            \
            float4 v = *(const float4*)&x[(row0 + r) * EMB + (K0) + c4];       \
            ushort4 u;                                                         \
            u.x = f2bf(v.x); u.y = f2bf(v.y); u.z = f2bf(v.z); u.w = f2bf(v.w);\
            *(ushort4*)&xs[BUF][r * 72 + c4] = u;                              \
        }                                                                      \
        for (int i = 0; i < 3; ++i) {  /* wt: 192 n x 64 k, 3 x b128/thr */    \
            int f = tid + i * 512;                                             \
            int n = f >> 3, kq = (f & 7) << 3;                                 \
            *(int4*)&ws[BUF][n * 72 + kq] =                                    \
                *(const int4*)&wt[(n << 10) + (K0) + kq];                      \
        }                                                                      \
    } while (0)

    STAGE(0, 0);
    __syncthreads();

    for (int kc = 0; kc < 16; ++kc) {
        const int cur = kc & 1;
        if (kc + 1 < 16) STAGE(cur ^ 1, (kc + 1) * 64);
        for (int kk = 0; kk < 2; ++kk) {
            bf16x8 a = *(const bf16x8*)&xs[cur][(wm * 16 + lid) * 72 + kk * 32 + quad * 8];
            for (int nt = 0; nt < 3; ++nt) {
                bf16x8 bfr = *(const bf16x8*)&ws[cur][(wn * 48 + nt * 16 + lid) * 72 + kk * 32 + quad * 8];
                acc[nt] = __builtin_amdgcn_mfma_f32_16x16x32_bf16(a, bfr, acc[nt], 0, 0, 0);
            }
        }
        __syncthreads();
    }
#undef STAGE

    for (int nt = 0; nt < 3; ++nt) {
        const int col = wn * 48 + nt * 16 + lid;
        const int mid = col >> 6;          // 0=Q 1=K 2=V, uniform per (wn,nt)
        const int lc  = col & 63;
        const float bias = (mid == 0) ? bq[lc] : (mid == 1) ? bk[lc] : bv[lc];
        const int rb = row0 + wm * 16 + quad * 4;   // + j
        f32x4 v = acc[nt];
        if (mid == 0) {
            for (int j = 0; j < 4; ++j)
                Qp[(rb + j) * 64 + lc] = f2bf((v[j] + bias) * QSCALE);
        } else if (mid == 1) {
            for (int j = 0; j < 4; ++j)
                Kp[(rb + j) * 64 + lc] = f2bf(v[j] + bias);
        } else {
            const int bb = rb >> 12, s = rb & 4095;  // rb%4==0 -> no straddle
            ushort4 u;
            u.x = f2bf(v[0] + bias); u.y = f2bf(v[1] + bias);
            u.z = f2bf(v[2] + bias); u.w = f2bf(v[3] + bias);
            *(ushort4*)&Vt[(bb * 64 + lc) * S_LEN + s] = u;
        }
    }
}

// ---------------------------------------------------------------------------
// Kernel 2: MFMA flash attention (causal), fixed-max softmax, barrier-free
// per-wave k-split, exact XCD/CU-balanced mapping + K-prefetch pipeline.
//   1D grid 512.  l%8 -> XCD (dispatch heuristic), batch = (l&7)&3 pins
//   batch b to XCDs {b, b+4} (1.5 MB working set, L2-resident).
//   qt partition: XCD-half h=0 covers qt {96..127}u{0..31} (slot0 heavy,
//   slot1 light), h=1 covers {64..95}u{32..63} -> every CU's two resident
//   blocks sum to ~65 k-tiles, every XCD exactly 2080.
//   Pipeline per iter: V(t) loads at top (hidden under QK+softmax),
//   K(t+8) prefetched after K(t)'s last MFMA use (hidden under P-roundtrip
//   + PV).  Block = 8 waves on one 32-row q-tile, 8-way k-split, private
//   (O,l), plain-sum LDS combine.  LDS 68.6 KB -> 2 blocks/CU.
// ---------------------------------------------------------------------------
__global__ __launch_bounds__(512, 4) void flash_kernel(
    const unsigned short* __restrict__ Qp, const unsigned short* __restrict__ Kp,
    const unsigned short* __restrict__ Vt, float* __restrict__ out) {

    __shared__ __align__(16) union {
        unsigned short Ps[8][2][16 * 72];                 // 36.9 KB (k-loop)
        struct { float Obuf[8][32][66]; float lbuf[8][32]; } c;  // 68.6 KB (combine)
    } sh;

    const int tid  = threadIdx.x;
    const int lane = tid & 63;
    const int w    = tid >> 6;        // 0..7 (k-split index)
    const int quad = lane >> 4;
    const int lid  = lane & 15;

    // balanced (XCD, CU, slot) -> (batch, qt) mapping
    const int l  = blockIdx.x;        // 0..511
    const int x  = l & 7;             // XCD (round-robin heuristic)
    const int m  = l >> 3;            // arrival index within XCD, 0..63
    const int j  = m & 31;            // CU within XCD
    const int r  = m >> 5;            // resident slot 0/1
    const int b  = x & 3;             // batch -> XCDs {b, b+4}
    const int h  = x >> 2;
    const int qt = (h == 0) ? (r ? j : 127 - j)
                            : (r ? 32 + j : 95 - j);
    const int q0 = qt * 32;
    const int nt = (q0 >> 6) + 1;     // 64-wide k tiles

    // Q A-frags (regs whole kernel): 2 m-tiles of 16 rows
    bf16x8 qf[2][2];
    for (int mt = 0; mt < 2; ++mt) {
        const int qrow = b * S_LEN + q0 + mt * 16 + lid;
        qf[mt][0] = *(const bf16x8*)&Qp[qrow * 64 + quad * 8];
        qf[mt][1] = *(const bf16x8*)&Qp[qrow * 64 + 32 + quad * 8];
    }

    const f32x4 zero = {0.f, 0.f, 0.f, 0.f};
    f32x4 O[2][4];
    for (int mt = 0; mt < 2; ++mt)
        for (int dt = 0; dt < 4; ++dt) O[mt][dt] = zero;
    float ls[2][4] = {{0.f, 0.f, 0.f, 0.f}, {0.f, 0.f, 0.f, 0.f}};

    const unsigned short* Kb = &Kp[b * S_LEN * 64];
    const unsigned short* Vb = &Vt[b * 64 * S_LEN];

    // prologue: K frags for first tile
    int t = w;
    bf16x8 kf[4][2];
    if (t < nt) {
        const int kt = t << 6;
        for (int sub = 0; sub < 4; ++sub) {
            const int krow = (kt + sub * 16 + lid) * 64;
            kf[sub][0] = *(const bf16x8*)&Kb[krow + quad * 8];
            kf[sub][1] = *(const bf16x8*)&Kb[krow + 32 + quad * 8];
        }
    }

    while (t < nt) {
        const int kt = t << 6;
        // ---- V(t) frags issued at top: consumed ~700 cyc later at PV
        bf16x8 vf[4][2];
        for (int sub = 0; sub < 4; ++sub) {
            const int vrow = (sub * 16 + lid) * S_LEN + kt;
            vf[sub][0] = *(const bf16x8*)&Vb[vrow + quad * 8];
            vf[sub][1] = *(const bf16x8*)&Vb[vrow + 32 + quad * 8];
        }
        // ---- QK^T for both m-tiles (last use of kf)
        f32x4 S0[4], S1[4];
        for (int sub = 0; sub < 4; ++sub) {
            S0[sub] = __builtin_amdgcn_mfma_f32_16x16x32_bf16(qf[0][0], kf[sub][0], zero, 0, 0, 0);
            S0[sub] = __builtin_amdgcn_mfma_f32_16x16x32_bf16(qf[0][1], kf[sub][1], S0[sub], 0, 0, 0);
            S1[sub] = __builtin_amdgcn_mfma_f32_16x16x32_bf16(qf[1][0], kf[sub][0], zero, 0, 0, 0);
            S1[sub] = __builtin_amdgcn_mfma_f32_16x16x32_bf16(qf[1][1], kf[sub][1], S1[sub], 0, 0, 0);
        }
        // ---- prefetch K(t+8) (hidden under softmax + P-roundtrip + PV)
        const int tn = t + 8;
        if (tn < nt) {
            const int ktn = tn << 6;
            for (int sub = 0; sub < 4; ++sub) {
                const int krow = (ktn + sub * 16 + lid) * 64;
                kf[sub][0] = *(const bf16x8*)&Kb[krow + quad * 8];
                kf[sub][1] = *(const bf16x8*)&Kb[krow + 32 + quad * 8];
            }
        }
        // ---- mask (diagonal tile), exp2, row-sum partials, P -> LDS
        if (t == nt - 1) {
            for (int sub = 0; sub < 4; ++sub) {
                const int kc = kt + sub * 16 + lid;
                for (int jj = 0; jj < 4; ++jj) {
                    if (kc > q0 + quad * 4 + jj)      S0[sub][jj] = -1e30f;
                    if (kc > q0 + 16 + quad * 4 + jj) S1[sub][jj] = -1e30f;
                }
            }
        }
        unsigned short* ps0 = &sh.Ps[w][0][0];
        unsigned short* ps1 = &sh.Ps[w][1][0];
        for (int sub = 0; sub < 4; ++sub)
            for (int jj = 0; jj < 4; ++jj) {
                const float p0 = exp2f(S0[sub][jj]);
                const float p1 = exp2f(S1[sub][jj]);
                ls[0][jj] += p0;
                ls[1][jj] += p1;
                ps0[(quad * 4 + jj) * 72 + sub * 16 + lid] = f2bf(p0);
                ps1[(quad * 4 + jj) * 72 + sub * 16 + lid] = f2bf(p1);
            }
        asm volatile("s_waitcnt lgkmcnt(0)" ::: "memory");
        bf16x8 pf[2][2];
        pf[0][0] = *(const bf16x8*)&ps0[lid * 72 + quad * 8];
        pf[0][1] = *(const bf16x8*)&ps0[lid * 72 + 32 + quad * 8];
        pf[1][0] = *(const bf16x8*)&ps1[lid * 72 + quad * 8];
        pf[1][1] = *(const bf16x8*)&ps1[lid * 72 + 32 + quad * 8];
        // ---- PV (vf arrived long ago; kf prefetch still in flight is fine)
        for (int dt = 0; dt < 4; ++dt)
            for (int mt = 0; mt < 2; ++mt) {
                O[mt][dt] = __builtin_amdgcn_mfma_f32_16x16x32_bf16(pf[mt][0], vf[dt][0], O[mt][dt], 0, 0, 0);
                O[mt][dt] = __builtin_amdgcn_mfma_f32_16x16x32_bf16(pf[mt][1], vf[dt][1], O[mt][dt], 0, 0, 0);
            }
        t = tn;
    }

    __syncthreads();   // all waves done with Ps before union reuse

    // ---- publish per-wave partials (l reduced over lid once per q-tile)
    for (int mt = 0; mt < 2; ++mt)
        for (int jj = 0; jj < 4; ++jj) {
            float rs = ls[mt][jj];
            for (int off = 1; off < 16; off <<= 1) rs += __shfl_xor(rs, off, 64);
            const int row = mt * 16 + quad * 4 + jj;
            if (lid == 0) sh.c.lbuf[w][row] = rs;
            for (int dt = 0; dt < 4; ++dt)
                sh.c.Obuf[w][row][dt * 16 + lid] = O[mt][dt][jj];
        }
    __syncthreads();

    // ---- combine: plain sums over 8 k-split partials; coalesced store
    const int col = tid & 63;
    const int r0  = tid >> 6;
    for (int ii = 0; ii < 4; ++ii) {
        const int row = r0 + ii * 8;
        float o = 0.f, lsum = 0.f;
        for (int ww = 0; ww < 8; ++ww) {
            o    += sh.c.Obuf[ww][row][col];
            lsum += sh.c.lbuf[ww][row];
        }
        out[(b * S_LEN + q0 + row) * 64 + col] = o / lsum;
    }
}

// ---------------------------------------------------------------------------
extern "C" void kernel_launch(void* const* d_in, const int* in_sizes, int n_in,
                              void* d_out, int out_size, void* d_ws, size_t ws_size,
                              hipStream_t stream) {
    const float* x  = (const float*)d_in[0];
    const float* Wq = (const float*)d_in[1];
    const float* bq = (const float*)d_in[2];
    const float* Wk = (const float*)d_in[3];
    const float* bk = (const float*)d_in[4];
    const float* Wv = (const float*)d_in[5];
    const float* bv = (const float*)d_in[6];
    float* out = (float*)d_out;

    unsigned short* wt = (unsigned short*)d_ws;   // 3*64*1024
    unsigned short* Qp = wt + 196608;             // 16384*64 each
    unsigned short* Kp = Qp + 1048576;
    unsigned short* Vt = Kp + 1048576;            // [b][64][4096]

    hipLaunchKernelGGL(wprep_kernel, dim3(48), dim3(256), 0, stream, Wq, Wk, Wv, wt);
    hipLaunchKernelGGL(qkv_kernel, dim3(512), dim3(512), 0, stream,
                       x, wt, bq, bk, bv, Qp, Kp, Vt);
    hipLaunchKernelGGL(flash_kernel, dim3(512), dim3(512), 0, stream,
                       Qp, Kp, Vt, out);
}

// Round 8
// 165.968 us; speedup vs baseline: 1.2025x; 1.2025x over previous
//
#include <hip/hip_runtime.h>
#include <stdint.h>

#define S_LEN 4096
#define EMB   1024
#define HEAD  64

typedef short bf16x8 __attribute__((ext_vector_type(8)));
typedef float f32x4  __attribute__((ext_vector_type(4)));

// scale = 1/sqrt(64) = 0.125, folded with log2(e) so softmax uses exp2
#define QSCALE 0.18033688011112042f

__device__ __forceinline__ unsigned short f2bf(float f) {
    union { float f; uint32_t u; } v; v.f = f;
    uint32_t r = v.u + 0x7fffu + ((v.u >> 16) & 1u);
    return (unsigned short)(r >> 16);
}

// ---------------------------------------------------------------------------
// Kernel 0: W prep.  wt[m][n][k] = bf16(W_m[k][n]).  Coalesced via LDS
// transpose: 48 blocks = 3 mats x 16 k-chunks of 64.
// ---------------------------------------------------------------------------
__global__ void wprep_kernel(const float* __restrict__ Wq,
                             const float* __restrict__ Wk,
                             const float* __restrict__ Wv,
                             unsigned short* __restrict__ wt) {
    __shared__ float t[64][65];
    const int tid = threadIdx.x;
    const int m   = blockIdx.x >> 4;
    const int k0  = (blockIdx.x & 15) << 6;
    const float* W = (m == 0) ? Wq : (m == 1) ? Wk : Wv;
    for (int i = 0; i < 4; ++i) {
        const int k  = (tid >> 4) + i * 16;
        const int n4 = (tid & 15) << 2;
        float4 v = *(const float4*)&W[(k0 + k) * 64 + n4];
        t[k][n4 + 0] = v.x; t[k][n4 + 1] = v.y;
        t[k][n4 + 2] = v.z; t[k][n4 + 3] = v.w;
    }
    __syncthreads();
    const int n = tid >> 2, kq = (tid & 3) << 4;
    __align__(16) unsigned short u[16];
    for (int i = 0; i < 16; ++i) u[i] = f2bf(t[kq + i][n]);
    *(int4*)&wt[(m * 64 + n) * 1024 + k0 + kq]     = *(int4*)&u[0];
    *(int4*)&wt[(m * 64 + n) * 1024 + k0 + kq + 8] = *(int4*)&u[8];
}

// ---------------------------------------------------------------------------
// Kernel 1: fused QKV projection, bf16 MFMA GEMM, double-buffered LDS.
//   M=16384 rows, K=1024, N=192.  512 blocks x 32-row tiles, 512 thr,
//   BK=64 (16 iters).  LDS 63 KB -> 2 blocks/CU; launch_bounds(512,2)
//   gives the 128-VGPR cap that matches (NOT (512,4): that caps at 64
//   and forces scratch spills -- R7 lesson).
// ---------------------------------------------------------------------------
__global__ __launch_bounds__(512, 2) void qkv_kernel(
    const float* __restrict__ x, const unsigned short* __restrict__ wt,
    const float* __restrict__ bq, const float* __restrict__ bk,
    const float* __restrict__ bv,
    unsigned short* __restrict__ Qp, unsigned short* __restrict__ Kp,
    unsigned short* __restrict__ Vt) {

    __shared__ __align__(16) unsigned short xs[2][32 * 72];   // 9.2 KB
    __shared__ __align__(16) unsigned short ws[2][192 * 72];  // 55.3 KB

    const int tid  = threadIdx.x;
    const int lane = tid & 63;
    const int w    = tid >> 6;        // 0..7
    const int wm   = w & 1;           // 0..1  (16-row half)
    const int wn   = w >> 1;          // 0..3  (48-col strip)
    const int quad = lane >> 4;
    const int lid  = lane & 15;
    const int row0 = blockIdx.x * 32;

    f32x4 acc[3];
    for (int j = 0; j < 3; ++j) acc[j] = (f32x4){0.f, 0.f, 0.f, 0.f};

#define STAGE(BUF, K0)                                                         \
    do {                                                                       \
        {   /* x: 32 rows x 64 k fp32 -> bf16, one float4 per thread */        \
            int r = tid >> 4, c4 = (tid & 15) << 2;                            \
            float4 v = *(const float4*)&x[(row0 + r) * EMB + (K0) + c4];       \
            ushort4 u;                                                         \
            u.x = f2bf(v.x); u.y = f2bf(v.y); u.z = f2bf(v.z); u.w = f2bf(v.w);\
            *(ushort4*)&xs[BUF][r * 72 + c4] = u;                              \
        }                                                                      \
        for (int i = 0; i < 3; ++i) {  /* wt: 192 n x 64 k, 3 x b128/thr */    \
            int f = tid + i * 512;                                             \
            int n = f >> 3, kq = (f & 7) << 3;                                 \
            *(int4*)&ws[BUF][n * 72 + kq] =                                    \
                *(const int4*)&wt[(n << 10) + (K0) + kq];                      \
        }                                                                      \
    } while (0)

    STAGE(0, 0);
    __syncthreads();

    for (int kc = 0; kc < 16; ++kc) {
        const int cur = kc & 1;
        if (kc + 1 < 16) STAGE(cur ^ 1, (kc + 1) * 64);
        for (int kk = 0; kk < 2; ++kk) {
            bf16x8 a = *(const bf16x8*)&xs[cur][(wm * 16 + lid) * 72 + kk * 32 + quad * 8];
            for (int nt = 0; nt < 3; ++nt) {
                bf16x8 bfr = *(const bf16x8*)&ws[cur][(wn * 48 + nt * 16 + lid) * 72 + kk * 32 + quad * 8];
                acc[nt] = __builtin_amdgcn_mfma_f32_16x16x32_bf16(a, bfr, acc[nt], 0, 0, 0);
            }
        }
        __syncthreads();
    }
#undef STAGE

    for (int nt = 0; nt < 3; ++nt) {
        const int col = wn * 48 + nt * 16 + lid;
        const int mid = col >> 6;          // 0=Q 1=K 2=V, uniform per (wn,nt)
        const int lc  = col & 63;
        const float bias = (mid == 0) ? bq[lc] : (mid == 1) ? bk[lc] : bv[lc];
        const int rb = row0 + wm * 16 + quad * 4;   // + j
        f32x4 v = acc[nt];
        if (mid == 0) {
            for (int j = 0; j < 4; ++j)
                Qp[(rb + j) * 64 + lc] = f2bf((v[j] + bias) * QSCALE);
        } else if (mid == 1) {
            for (int j = 0; j < 4; ++j)
                Kp[(rb + j) * 64 + lc] = f2bf(v[j] + bias);
        } else {
            const int bb = rb >> 12, s = rb & 4095;  // rb%4==0 -> no straddle
            ushort4 u;
            u.x = f2bf(v[0] + bias); u.y = f2bf(v[1] + bias);
            u.z = f2bf(v[2] + bias); u.w = f2bf(v[3] + bias);
            *(ushort4*)&Vt[(bb * 64 + lc) * S_LEN + s] = u;
        }
    }
}

// ---------------------------------------------------------------------------
// Kernel 2: MFMA flash attention (causal), fixed-max softmax, barrier-free
// per-wave k-split, exact XCD/CU-balanced mapping + K-prefetch pipeline.
//   Identical to R7 EXCEPT launch_bounds(512,2): 128-VGPR cap so the
//   V-early + K-prefetch liveness (~110 VGPRs) fits without scratch
//   spills (R7 at the 64-VGPR cap spilled ~200 MB/launch to HBM).
//   LDS 68.6 KB limits to 2 blocks/CU either way -- occupancy unchanged.
// ---------------------------------------------------------------------------
__global__ __launch_bounds__(512, 2) void flash_kernel(
    const unsigned short* __restrict__ Qp, const unsigned short* __restrict__ Kp,
    const unsigned short* __restrict__ Vt, float* __restrict__ out) {

    __shared__ __align__(16) union {
        unsigned short Ps[8][2][16 * 72];                 // 36.9 KB (k-loop)
        struct { float Obuf[8][32][66]; float lbuf[8][32]; } c;  // 68.6 KB (combine)
    } sh;

    const int tid  = threadIdx.x;
    const int lane = tid & 63;
    const int w    = tid >> 6;        // 0..7 (k-split index)
    const int quad = lane >> 4;
    const int lid  = lane & 15;

    // balanced (XCD, CU, slot) -> (batch, qt) mapping (l%8 -> XCD verified
    // by R6 FETCH=5.6MB ~= compulsory with single-batch-per-XCD pinning)
    const int l  = blockIdx.x;        // 0..511
    const int x  = l & 7;             // XCD
    const int m  = l >> 3;            // arrival index within XCD, 0..63
    const int j  = m & 31;            // CU within XCD
    const int r  = m >> 5;            // resident slot 0/1
    const int b  = x & 3;             // batch -> XCDs {b, b+4}
    const int h  = x >> 2;
    const int qt = (h == 0) ? (r ? j : 127 - j)
                            : (r ? 32 + j : 95 - j);
    const int q0 = qt * 32;
    const int nt = (q0 >> 6) + 1;     // 64-wide k tiles

    // Q A-frags (regs whole kernel): 2 m-tiles of 16 rows
    bf16x8 qf[2][2];
    for (int mt = 0; mt < 2; ++mt) {
        const int qrow = b * S_LEN + q0 + mt * 16 + lid;
        qf[mt][0] = *(const bf16x8*)&Qp[qrow * 64 + quad * 8];
        qf[mt][1] = *(const bf16x8*)&Qp[qrow * 64 + 32 + quad * 8];
    }

    const f32x4 zero = {0.f, 0.f, 0.f, 0.f};
    f32x4 O[2][4];
    for (int mt = 0; mt < 2; ++mt)
        for (int dt = 0; dt < 4; ++dt) O[mt][dt] = zero;
    float ls[2][4] = {{0.f, 0.f, 0.f, 0.f}, {0.f, 0.f, 0.f, 0.f}};

    const unsigned short* Kb = &Kp[b * S_LEN * 64];
    const unsigned short* Vb = &Vt[b * 64 * S_LEN];

    // prologue: K frags for first tile
    int t = w;
    bf16x8 kf[4][2];
    if (t < nt) {
        const int kt = t << 6;
        for (int sub = 0; sub < 4; ++sub) {
            const int krow = (kt + sub * 16 + lid) * 64;
            kf[sub][0] = *(const bf16x8*)&Kb[krow + quad * 8];
            kf[sub][1] = *(const bf16x8*)&Kb[krow + 32 + quad * 8];
        }
    }

    while (t < nt) {
        const int kt = t << 6;
        // ---- V(t) frags issued at top: consumed ~700 cyc later at PV
        bf16x8 vf[4][2];
        for (int sub = 0; sub < 4; ++sub) {
            const int vrow = (sub * 16 + lid) * S_LEN + kt;
            vf[sub][0] = *(const bf16x8*)&Vb[vrow + quad * 8];
            vf[sub][1] = *(const bf16x8*)&Vb[vrow + 32 + quad * 8];
        }
        // ---- QK^T for both m-tiles (last use of kf)
        f32x4 S0[4], S1[4];
        for (int sub = 0; sub < 4; ++sub) {
            S0[sub] = __builtin_amdgcn_mfma_f32_16x16x32_bf16(qf[0][0], kf[sub][0], zero, 0, 0, 0);
            S0[sub] = __builtin_amdgcn_mfma_f32_16x16x32_bf16(qf[0][1], kf[sub][1], S0[sub], 0, 0, 0);
            S1[sub] = __builtin_amdgcn_mfma_f32_16x16x32_bf16(qf[1][0], kf[sub][0], zero, 0, 0, 0);
            S1[sub] = __builtin_amdgcn_mfma_f32_16x16x32_bf16(qf[1][1], kf[sub][1], S1[sub], 0, 0, 0);
        }
        // ---- prefetch K(t+8) (hidden under softmax + P-roundtrip + PV)
        const int tn = t + 8;
        if (tn < nt) {
            const int ktn = tn << 6;
            for (int sub = 0; sub < 4; ++sub) {
                const int krow = (ktn + sub * 16 + lid) * 64;
                kf[sub][0] = *(const bf16x8*)&Kb[krow + quad * 8];
                kf[sub][1] = *(const bf16x8*)&Kb[krow + 32 + quad * 8];
            }
        }
        // ---- mask (diagonal tile), exp2, row-sum partials, P -> LDS
        if (t == nt - 1) {
            for (int sub = 0; sub < 4; ++sub) {
                const int kc = kt + sub * 16 + lid;
                for (int jj = 0; jj < 4; ++jj) {
                    if (kc > q0 + quad * 4 + jj)      S0[sub][jj] = -1e30f;
                    if (kc > q0 + 16 + quad * 4 + jj) S1[sub][jj] = -1e30f;
                }
            }
        }
        unsigned short* ps0 = &sh.Ps[w][0][0];
        unsigned short* ps1 = &sh.Ps[w][1][0];
        for (int sub = 0; sub < 4; ++sub)
            for (int jj = 0; jj < 4; ++jj) {
                const float p0 = exp2f(S0[sub][jj]);
                const float p1 = exp2f(S1[sub][jj]);
                ls[0][jj] += p0;
                ls[1][jj] += p1;
                ps0[(quad * 4 + jj) * 72 + sub * 16 + lid] = f2bf(p0);
                ps1[(quad * 4 + jj) * 72 + sub * 16 + lid] = f2bf(p1);
            }
        asm volatile("s_waitcnt lgkmcnt(0)" ::: "memory");
        bf16x8 pf[2][2];
        pf[0][0] = *(const bf16x8*)&ps0[lid * 72 + quad * 8];
        pf[0][1] = *(const bf16x8*)&ps0[lid * 72 + 32 + quad * 8];
        pf[1][0] = *(const bf16x8*)&ps1[lid * 72 + quad * 8];
        pf[1][1] = *(const bf16x8*)&ps1[lid * 72 + 32 + quad * 8];
        // ---- PV (vf arrived long ago; kf prefetch still in flight is fine)
        for (int dt = 0; dt < 4; ++dt)
            for (int mt = 0; mt < 2; ++mt) {
                O[mt][dt] = __builtin_amdgcn_mfma_f32_16x16x32_bf16(pf[mt][0], vf[dt][0], O[mt][dt], 0, 0, 0);
                O[mt][dt] = __builtin_amdgcn_mfma_f32_16x16x32_bf16(pf[mt][1], vf[dt][1], O[mt][dt], 0, 0, 0);
            }
        t = tn;
    }

    __syncthreads();   // all waves done with Ps before union reuse

    // ---- publish per-wave partials (l reduced over lid once per q-tile)
    for (int mt = 0; mt < 2; ++mt)
        for (int jj = 0; jj < 4; ++jj) {
            float rs = ls[mt][jj];
            for (int off = 1; off < 16; off <<= 1) rs += __shfl_xor(rs, off, 64);
            const int row = mt * 16 + quad * 4 + jj;
            if (lid == 0) sh.c.lbuf[w][row] = rs;
            for (int dt = 0; dt < 4; ++dt)
                sh.c.Obuf[w][row][dt * 16 + lid] = O[mt][dt][jj];
        }
    __syncthreads();

    // ---- combine: plain sums over 8 k-split partials; coalesced store
    const int col = tid & 63;
    const int r0  = tid >> 6;
    for (int ii = 0; ii < 4; ++ii) {
        const int row = r0 + ii * 8;
        float o = 0.f, lsum = 0.f;
        for (int ww = 0; ww < 8; ++ww) {
            o    += sh.c.Obuf[ww][row][col];
            lsum += sh.c.lbuf[ww][row];
        }
        out[(b * S_LEN + q0 + row) * 64 + col] = o / lsum;
    }
}

// ---------------------------------------------------------------------------
extern "C" void kernel_launch(void* const* d_in, const int* in_sizes, int n_in,
                              void* d_out, int out_size, void* d_ws, size_t ws_size,
                              hipStream_t stream) {
    const float* x  = (const float*)d_in[0];
    const float* Wq = (const float*)d_in[1];
    const float* bq = (const float*)d_in[2];
    const float* Wk = (const float*)d_in[3];
    const float* bk = (const float*)d_in[4];
    const float* Wv = (const float*)d_in[5];
    const float* bv = (const float*)d_in[6];
    float* out = (float*)d_out;

    unsigned short* wt = (unsigned short*)d_ws;   // 3*64*1024
    unsigned short* Qp = wt + 196608;             // 16384*64 each
    unsigned short* Kp = Qp + 1048576;
    unsigned short* Vt = Kp + 1048576;            // [b][64][4096]

    hipLaunchKernelGGL(wprep_kernel, dim3(48), dim3(256), 0, stream, Wq, Wk, Wv, wt);
    hipLaunchKernelGGL(qkv_kernel, dim3(512), dim3(512), 0, stream,
                       x, wt, bq, bk, bv, Qp, Kp, Vt);
    hipLaunchKernelGGL(flash_kernel, dim3(512), dim3(512), 0, stream,
                       Qp, Kp, Vt, out);
}